// Round 2
// baseline (321.004 us; speedup 1.0000x reference)
//
#include <hip/hip_runtime.h>

// B=64,T=128,D=U=1024. M=B*T=8192 rows, independent (no time recurrence).
//   h' = reset ? 0 : state
//   z = sig(x@wi_z + h'@wh_z + bz) ; r = sig(x@wi_r + h'@wh_r + br)
//   a = tanh(x@wi_a + (r*h')@wh_a + ba)     // NOTE: (r*h') @ w  (Python * and @ same precedence!)
//   h_new = (1-z)*h' + z*a ; out = [h_new, h_new]
// 3 phases: weight transpose->bf16; zr gates (writes z fp32 -> d_out 2nd half, rh bf16 -> ws);
//           candidate GEMM (x@wi_a + rh@wh_a) + gating epilogue.

typedef __attribute__((ext_vector_type(8))) short short8;
typedef __attribute__((ext_vector_type(4))) short short4v;
typedef __attribute__((ext_vector_type(4))) float floatx4;
typedef __attribute__((ext_vector_type(4))) float f32x4;

#define MROWS 8192
#define KD 1024
#define NU 1024
#define BM 64
#define BN 64
#define BK 32
#define LDK 40  // padded LDS row stride (shorts): 80B stride -> 2-way bank alias (free, m136)

__device__ __forceinline__ short f2bf(float f) {
  unsigned u = __builtin_bit_cast(unsigned, f);
  u += 0x7fffu + ((u >> 16) & 1u);  // RNE
  return (short)(u >> 16);
}
__device__ __forceinline__ float bf2f(short s) {
  unsigned u = ((unsigned)(unsigned short)s) << 16;
  return __builtin_bit_cast(float, u);
}
__device__ __forceinline__ float sigmoid_f(float v) { return 1.f / (1.f + __expf(-v)); }
__device__ __forceinline__ float tanh_f(float v) {
  float c = fminf(fmaxf(v, -15.f), 15.f);
  float e = __expf(2.f * c);
  return (e - 1.f) / (e + 1.f);
}

// w [1024][3072] fp32 -> wT [3072][1024] bf16 (K-contiguous rows = MFMA B frags)
__global__ __launch_bounds__(256) void wt_kernel(const float* __restrict__ w,
                                                 short* __restrict__ wT) {
  __shared__ float tile[32][33];
  const int kb = blockIdx.x * 32;
  const int nb = blockIdx.y * 32;
  const int tx = threadIdx.x & 31;
  const int ty = threadIdx.x >> 5;
#pragma unroll
  for (int r = 0; r < 32; r += 8)
    tile[ty + r][tx] = w[(size_t)(kb + ty + r) * 3072 + nb + tx];
  __syncthreads();
#pragma unroll
  for (int r = 0; r < 32; r += 8)
    wT[(size_t)(nb + ty + r) * KD + kb + tx] = f2bf(tile[tx][ty + r]);
}

// ---------------- Phase 1: z and r gates ----------------
__global__ __launch_bounds__(256, 2) void zr_kernel(
    const float* __restrict__ x, const int* __restrict__ reset,
    const float* __restrict__ state, const short* __restrict__ wiT,
    const short* __restrict__ whT, const float* __restrict__ bias,
    float* __restrict__ zout, short* __restrict__ rh) {
  __shared__ short sX[BM][LDK];
  __shared__ short sH[BM][LDK];
  __shared__ short sW[4][BN][LDK];  // 0:wi_z 1:wh_z 2:wi_r 3:wh_r

  const int tid = threadIdx.x;
  const int bid = blockIdx.x;
  const int swz = (bid & 7) * 256 + (bid >> 3);  // XCD-chunked
  const int n0 = (swz >> 7) * BN;
  const int m0 = (swz & 127) * BM;

  const int lane = tid & 63;
  const int wave = tid >> 6;
  const int wr = (wave >> 1) * 32;
  const int wc = (wave & 1) * 32;
  const int lrow = lane & 15;
  const int lk = (lane >> 4) * 8;

  const f32x4 z4 = {0.f, 0.f, 0.f, 0.f};
  f32x4 accZ[2][2], accR[2][2];
#pragma unroll
  for (int i = 0; i < 2; ++i)
#pragma unroll
    for (int j = 0; j < 2; ++j) { accZ[i][j] = z4; accR[i][j] = z4; }

  const int arow = tid >> 3;
  const int aco = (tid & 7) * 4;
  const float hm0 = reset[m0 + arow] ? 0.f : 1.f;
  const float hm1 = reset[m0 + arow + 32] ? 0.f : 1.f;
  const float* xs0 = x + (size_t)(m0 + arow) * KD + aco;
  const float* xs1 = x + (size_t)(m0 + arow + 32) * KD + aco;
  const float* hs0 = state + (size_t)(m0 + arow) * KD + aco;
  const float* hs1 = state + (size_t)(m0 + arow + 32) * KD + aco;

  const int wrow = tid >> 2;
  const int wko = (tid & 3) * 8;
  const short* wsrc0 = wiT + (size_t)(n0 + wrow) * KD + wko;           // wi_z
  const short* wsrc1 = whT + (size_t)(n0 + wrow) * KD + wko;           // wh_z
  const short* wsrc2 = wiT + (size_t)(NU + n0 + wrow) * KD + wko;      // wi_r
  const short* wsrc3 = whT + (size_t)(NU + n0 + wrow) * KD + wko;      // wh_r

  for (int kk = 0; kk < KD; kk += BK) {
    {
      floatx4 fx0 = *(const floatx4*)(xs0 + kk);
      floatx4 fh0 = *(const floatx4*)(hs0 + kk);
      floatx4 fx1 = *(const floatx4*)(xs1 + kk);
      floatx4 fh1 = *(const floatx4*)(hs1 + kk);
      short4v cx0, ch0, cx1, ch1;
#pragma unroll
      for (int e = 0; e < 4; ++e) {
        cx0[e] = f2bf(fx0[e]); ch0[e] = f2bf(fh0[e] * hm0);
        cx1[e] = f2bf(fx1[e]); ch1[e] = f2bf(fh1[e] * hm1);
      }
      *(short4v*)&sX[arow][aco] = cx0;
      *(short4v*)&sH[arow][aco] = ch0;
      *(short4v*)&sX[arow + 32][aco] = cx1;
      *(short4v*)&sH[arow + 32][aco] = ch1;
    }
    *(short8*)&sW[0][wrow][wko] = *(const short8*)(wsrc0 + kk);
    *(short8*)&sW[1][wrow][wko] = *(const short8*)(wsrc1 + kk);
    *(short8*)&sW[2][wrow][wko] = *(const short8*)(wsrc2 + kk);
    *(short8*)&sW[3][wrow][wko] = *(const short8*)(wsrc3 + kk);
    __syncthreads();

    short8 ax0 = *(const short8*)&sX[wr + lrow][lk];
    short8 ax1 = *(const short8*)&sX[wr + 16 + lrow][lk];
    short8 ah0 = *(const short8*)&sH[wr + lrow][lk];
    short8 ah1 = *(const short8*)&sH[wr + 16 + lrow][lk];
#pragma unroll
    for (int j = 0; j < 2; ++j) {
      const int bc = wc + j * 16 + lrow;
      short8 bzi = *(const short8*)&sW[0][bc][lk];
      short8 bzh = *(const short8*)&sW[1][bc][lk];
      short8 bri = *(const short8*)&sW[2][bc][lk];
      short8 brh = *(const short8*)&sW[3][bc][lk];
      accZ[0][j] = __builtin_amdgcn_mfma_f32_16x16x32_bf16(ax0, bzi, accZ[0][j], 0, 0, 0);
      accZ[1][j] = __builtin_amdgcn_mfma_f32_16x16x32_bf16(ax1, bzi, accZ[1][j], 0, 0, 0);
      accZ[0][j] = __builtin_amdgcn_mfma_f32_16x16x32_bf16(ah0, bzh, accZ[0][j], 0, 0, 0);
      accZ[1][j] = __builtin_amdgcn_mfma_f32_16x16x32_bf16(ah1, bzh, accZ[1][j], 0, 0, 0);
      accR[0][j] = __builtin_amdgcn_mfma_f32_16x16x32_bf16(ax0, bri, accR[0][j], 0, 0, 0);
      accR[1][j] = __builtin_amdgcn_mfma_f32_16x16x32_bf16(ax1, bri, accR[1][j], 0, 0, 0);
      accR[0][j] = __builtin_amdgcn_mfma_f32_16x16x32_bf16(ah0, brh, accR[0][j], 0, 0, 0);
      accR[1][j] = __builtin_amdgcn_mfma_f32_16x16x32_bf16(ah1, brh, accR[1][j], 0, 0, 0);
    }
    __syncthreads();
  }

#pragma unroll
  for (int j = 0; j < 2; ++j) {
    const int gc = n0 + wc + j * 16 + lrow;
    const float bz = bias[gc];
    const float br = bias[NU + gc];
#pragma unroll
    for (int i = 0; i < 2; ++i) {
#pragma unroll
      for (int rg = 0; rg < 4; ++rg) {
        const int gr = m0 + wr + i * 16 + (lane >> 4) * 4 + rg;
        const float zv = sigmoid_f(accZ[i][j][rg] + bz);
        const float rv = sigmoid_f(accR[i][j][rg] + br);
        const float hv = reset[gr] ? 0.f : state[(size_t)gr * NU + gc];
        zout[(size_t)gr * NU + gc] = zv;
        rh[(size_t)gr * NU + gc] = f2bf(rv * hv);
      }
    }
  }
}

// ---------------- Phase 2: candidate GEMM + gating ----------------
__global__ __launch_bounds__(256, 2) void cand_kernel(
    const float* __restrict__ x, const int* __restrict__ reset,
    const float* __restrict__ state, const short* __restrict__ wiT,
    const short* __restrict__ whT, const float* __restrict__ bias,
    const short* __restrict__ rh, const float* __restrict__ zbuf,
    float* __restrict__ out) {
  __shared__ short sA[BM][LDK];
  __shared__ short sB[BN][LDK];

  const int tid = threadIdx.x;
  const int bid = blockIdx.x;
  const int swz = (bid & 7) * 256 + (bid >> 3);
  const int n0 = (swz >> 7) * BN;
  const int m0 = (swz & 127) * BM;

  const int lane = tid & 63;
  const int wave = tid >> 6;
  const int wr = (wave >> 1) * 32;
  const int wc = (wave & 1) * 32;
  const int lrow = lane & 15;
  const int lk = (lane >> 4) * 8;

  const f32x4 z4 = {0.f, 0.f, 0.f, 0.f};
  f32x4 acc[2][2];
#pragma unroll
  for (int i = 0; i < 2; ++i)
#pragma unroll
    for (int j = 0; j < 2; ++j) acc[i][j] = z4;

  const int arow = tid >> 3;
  const int aco = (tid & 7) * 4;
  const float* xs0 = x + (size_t)(m0 + arow) * KD + aco;
  const float* xs1 = x + (size_t)(m0 + arow + 32) * KD + aco;

  const int wrow = tid >> 2;
  const int wko = (tid & 3) * 8;
  const short* bsrc_i = wiT + (size_t)(2 * NU + n0 + wrow) * KD + wko;  // wi_a
  const short* bsrc_h = whT + (size_t)(2 * NU + n0 + wrow) * KD + wko;  // wh_a
  const short* asrc_rh = rh + (size_t)(m0 + wrow) * NU + wko;

  // Loop 1: x @ wi_a
  for (int kk = 0; kk < KD; kk += BK) {
    {
      floatx4 fx0 = *(const floatx4*)(xs0 + kk);
      floatx4 fx1 = *(const floatx4*)(xs1 + kk);
      short4v cx0, cx1;
#pragma unroll
      for (int e = 0; e < 4; ++e) { cx0[e] = f2bf(fx0[e]); cx1[e] = f2bf(fx1[e]); }
      *(short4v*)&sA[arow][aco] = cx0;
      *(short4v*)&sA[arow + 32][aco] = cx1;
    }
    *(short8*)&sB[wrow][wko] = *(const short8*)(bsrc_i + kk);
    __syncthreads();

    short8 a0 = *(const short8*)&sA[wr + lrow][lk];
    short8 a1 = *(const short8*)&sA[wr + 16 + lrow][lk];
#pragma unroll
    for (int j = 0; j < 2; ++j) {
      short8 b = *(const short8*)&sB[wc + j * 16 + lrow][lk];
      acc[0][j] = __builtin_amdgcn_mfma_f32_16x16x32_bf16(a0, b, acc[0][j], 0, 0, 0);
      acc[1][j] = __builtin_amdgcn_mfma_f32_16x16x32_bf16(a1, b, acc[1][j], 0, 0, 0);
    }
    __syncthreads();
  }
  // Loop 2: rh @ wh_a  (rh already bf16, K-contiguous)
  for (int kk = 0; kk < KD; kk += BK) {
    *(short8*)&sA[wrow][wko] = *(const short8*)(asrc_rh + kk);
    *(short8*)&sB[wrow][wko] = *(const short8*)(bsrc_h + kk);
    __syncthreads();

    short8 a0 = *(const short8*)&sA[wr + lrow][lk];
    short8 a1 = *(const short8*)&sA[wr + 16 + lrow][lk];
#pragma unroll
    for (int j = 0; j < 2; ++j) {
      short8 b = *(const short8*)&sB[wc + j * 16 + lrow][lk];
      acc[0][j] = __builtin_amdgcn_mfma_f32_16x16x32_bf16(a0, b, acc[0][j], 0, 0, 0);
      acc[1][j] = __builtin_amdgcn_mfma_f32_16x16x32_bf16(a1, b, acc[1][j], 0, 0, 0);
    }
    __syncthreads();
  }

#pragma unroll
  for (int j = 0; j < 2; ++j) {
    const int gc = n0 + wc + j * 16 + lrow;
    const float ba = bias[2 * NU + gc];
#pragma unroll
    for (int i = 0; i < 2; ++i) {
#pragma unroll
      for (int rg = 0; rg < 4; ++rg) {
        const int gr = m0 + wr + i * 16 + (lane >> 4) * 4 + rg;
        const float av = tanh_f(acc[i][j][rg] + ba);
        const float zv = zbuf[(size_t)gr * NU + gc];
        const float hv = reset[gr] ? 0.f : state[(size_t)gr * NU + gc];
        const float hn = (1.f - zv) * hv + zv * av;
        out[(size_t)gr * NU + gc] = hn;
        out[(size_t)MROWS * NU + (size_t)gr * NU + gc] = hn;  // overwrites zbuf slot (same thread, read-first)
      }
    }
  }
}

extern "C" void kernel_launch(void* const* d_in, const int* in_sizes, int n_in,
                              void* d_out, int out_size, void* d_ws, size_t ws_size,
                              hipStream_t stream) {
  const float* x = (const float*)d_in[0];      // 8192*1024
  const int* reset = (const int*)d_in[1];      // 8192
  const float* state = (const float*)d_in[2];  // 8192*1024
  const float* w_i = (const float*)d_in[3];    // 1024*3072
  const float* w_h = (const float*)d_in[4];    // 1024*3072
  const float* bias = (const float*)d_in[5];   // 3072
  float* out = (float*)d_out;                  // 2 * 8192*1024 fp32

  short* wiT = (short*)d_ws;                       // [3072][1024] bf16
  short* whT = wiT + (size_t)3072 * 1024;          // [3072][1024] bf16
  short* rh = whT + (size_t)3072 * 1024;           // [8192][1024] bf16
  float* zbuf = out + (size_t)MROWS * NU;          // z stored in d_out 2nd half (fp32), overwritten by new_state

  dim3 tg(KD / 32, 3072 / 32);
  wt_kernel<<<tg, 256, 0, stream>>>(w_i, wiT);
  wt_kernel<<<tg, 256, 0, stream>>>(w_h, whT);

  zr_kernel<<<dim3((MROWS / BM) * (NU / BN)), 256, 0, stream>>>(
      x, reset, state, wiT, whT, bias, zbuf, rh);
  cand_kernel<<<dim3((MROWS / BM) * (NU / BN)), 256, 0, stream>>>(
      x, reset, state, wiT, whT, bias, rh, zbuf, out);
}

// Round 3
// 196.682 us; speedup vs baseline: 1.6321x; 1.6321x over previous
//
#include <hip/hip_runtime.h>

// B=64,T=128,D=U=1024. M=8192 independent rows.
//   h' = reset?0:state
//   z = sig(x@wi_z + h'@wh_z + bz); r = sig(x@wi_r + h'@wh_r + br)
//   a = tanh(x@wi_a + (r*h')@wh_a + ba)   // (r*h') @ w  — * binds left of @
//   h_new = (1-z)h' + z*a; out = [h_new, h_new]
// Round 3: all-bf16 GEMMs, m97-style 128^2 tiles + global_load_lds(16B).
//   prep: Wc[3072][2048] bf16 = [[wi|wh] rows], xbf/hbf bf16
//   zr:   GEMM M8192 N2048 K2048, epi -> z (fp32, d_out 2nd half) and rh bf16
//   cand: GEMM M8192 N1024 K2048 (A=[xbf|rh]), epi -> gating, write both outs
// ws: Wc 12MB + xbf 16MB + hbf 16MB + rh 16MB = 60MB.

typedef __attribute__((ext_vector_type(8))) short short8;
typedef __attribute__((ext_vector_type(4))) short short4v;
typedef __attribute__((ext_vector_type(4))) float floatx4;
typedef __attribute__((ext_vector_type(4))) float f32x4;

#define MROWS 8192
#define KTOT 2048
#define NU 1024

__device__ __forceinline__ short f2bf(float f) {
  unsigned u = __builtin_bit_cast(unsigned, f);
  u += 0x7fffu + ((u >> 16) & 1u);  // RNE
  return (short)(u >> 16);
}
__device__ __forceinline__ float bf2f(short s) {
  unsigned u = ((unsigned)(unsigned short)s) << 16;
  return __builtin_bit_cast(float, u);
}
__device__ __forceinline__ float sigmoid_f(float v) { return 1.f / (1.f + __expf(-v)); }
__device__ __forceinline__ float tanh_f(float v) {
  float c = fminf(fmaxf(v, -15.f), 15.f);
  float e = __expf(2.f * c);
  return (e - 1.f) / (e + 1.f);
}

typedef __attribute__((address_space(3))) void* lds_vp;
typedef const __attribute__((address_space(1))) void* gbl_vp;
__device__ __forceinline__ void gload16(const void* g, void* lds) {
  __builtin_amdgcn_global_load_lds((gbl_vp)g, (lds_vp)lds, 16, 0, 0);
}

// ---- prep 1: Wc[n][k] = (k<1024 ? w_i[k][n] : w_h[k-1024][n]) as bf16 ----
// w_i/w_h are [1024][3072] fp32; Wc is [3072][2048] bf16 (K-contiguous rows).
__global__ __launch_bounds__(256) void wt_kernel(const float* __restrict__ w_i,
                                                 const float* __restrict__ w_h,
                                                 short* __restrict__ Wc) {
  __shared__ float tile[32][33];
  const int kb = blockIdx.x * 32;   // 0..2047
  const int nb = blockIdx.y * 32;   // 0..3071
  const float* src = (kb < 1024) ? w_i : w_h;
  const int kbl = kb & 1023;
  const int tx = threadIdx.x & 31;
  const int ty = threadIdx.x >> 5;
#pragma unroll
  for (int r = 0; r < 32; r += 8)
    tile[ty + r][tx] = src[(size_t)(kbl + ty + r) * 3072 + nb + tx];
  __syncthreads();
#pragma unroll
  for (int r = 0; r < 32; r += 8)
    Wc[(size_t)(nb + ty + r) * KTOT + kb + tx] = f2bf(tile[tx][ty + r]);
}

// ---- prep 2: xbf = bf16(x); hbf = bf16(reset ? 0 : state) ----
__global__ __launch_bounds__(256) void xh_kernel(const float* __restrict__ x,
                                                 const int* __restrict__ reset,
                                                 const float* __restrict__ state,
                                                 short* __restrict__ xbf,
                                                 short* __restrict__ hbf) {
  const size_t i4 = (size_t)blockIdx.x * blockDim.x + threadIdx.x;
  const size_t off = i4 * 4;
  const int row = (int)(off >> 10);
  const float hm = reset[row] ? 0.f : 1.f;
  floatx4 fx = *(const floatx4*)(x + off);
  floatx4 fh = *(const floatx4*)(state + off);
  short4v cx, ch;
#pragma unroll
  for (int e = 0; e < 4; ++e) { cx[e] = f2bf(fx[e]); ch[e] = f2bf(fh[e] * hm); }
  *(short4v*)(xbf + off) = cx;
  *(short4v*)(hbf + off) = ch;
}

// ---- shared GEMM core: 128x128 tile, BK=32, 4 waves, global_load_lds ----
// sA/sB: [128][32] bf16 linear (gload_lds-compatible).
struct TilePtrs {
  const short* a0; const short* a1;  // chunk rows 0..63 / 64..127 (x-half base)
  const short* h0; const short* h1;  // second-K-half base (hbf or rh)
  const short* b0; const short* b1;
};

#define GEMM_CORE(KHALF_SWITCH)                                              \
  f32x4 acc[4][4];                                                           \
  _Pragma("unroll") for (int i = 0; i < 4; ++i)                              \
      _Pragma("unroll") for (int j = 0; j < 4; ++j)                          \
          acc[i][j] = (f32x4){0.f, 0.f, 0.f, 0.f};                           \
  const int wave = tid >> 6, lane = tid & 63;                                \
  const int wm = wave >> 1, wn = wave & 1;                                   \
  const int lrow = lane & 15, lk = (lane >> 4) * 8;                          \
  char* ldsA0 = (char*)sA + wave * 1024; char* ldsA1 = ldsA0 + 4096;         \
  char* ldsB0 = (char*)sB + wave * 1024; char* ldsB1 = ldsB0 + 4096;         \
  for (int kk = 0; kk < KTOT; kk += 32) {                                    \
    const int kl = kk & 1023;                                                \
    const short *pa0, *pa1;                                                  \
    KHALF_SWITCH                                                             \
    gload16(pa0, ldsA0);                                                     \
    gload16(pa1, ldsA1);                                                     \
    gload16(p.b0 + kk, ldsB0);                                               \
    gload16(p.b1 + kk, ldsB1);                                               \
    __syncthreads();                                                         \
    short8 af[4], bfr[4];                                                    \
    _Pragma("unroll") for (int i = 0; i < 4; ++i)                            \
        af[i] = *(const short8*)&sA[wm * 64 + i * 16 + lrow][lk];            \
    _Pragma("unroll") for (int j = 0; j < 4; ++j)                            \
        bfr[j] = *(const short8*)&sB[wn * 64 + j * 16 + lrow][lk];           \
    _Pragma("unroll") for (int i = 0; i < 4; ++i)                            \
        _Pragma("unroll") for (int j = 0; j < 4; ++j)                        \
            acc[i][j] = __builtin_amdgcn_mfma_f32_16x16x32_bf16(             \
                af[i], bfr[j], acc[i][j], 0, 0, 0);                          \
    __syncthreads();                                                         \
  }

#define KSWITCH_STD                                                          \
  if (kk < 1024) { pa0 = p.a0 + kl; pa1 = p.a1 + kl; }                       \
  else           { pa0 = p.h0 + kl; pa1 = p.h1 + kl; }

// ---- phase 1: zr GEMM (N=2048) ----
__global__ __launch_bounds__(256, 3) void zr_kernel(
    const short* __restrict__ xbf, const short* __restrict__ hbf,
    const short* __restrict__ Wc, const float* __restrict__ bias,
    float* __restrict__ zbuf, short* __restrict__ rh) {
  __shared__ short sA[128][32];
  __shared__ short sB[128][32];
  const int tid = threadIdx.x;
  // bijective XCD chunking; within chunk: M-tile-major (A reuse in L2)
  const int widx = (blockIdx.x & 7) * 128 + (blockIdx.x >> 3);
  const int m0 = (widx >> 4) * 128;       // 64 M-tiles
  const int n0 = (widx & 15) * 128;       // 16 N-tiles over 2048

  const int r0 = tid >> 2;
  const int kc = (tid & 3) * 8;
  TilePtrs p;
  p.a0 = xbf + (size_t)(m0 + r0) * 1024 + kc;
  p.a1 = xbf + (size_t)(m0 + 64 + r0) * 1024 + kc;
  p.h0 = hbf + (size_t)(m0 + r0) * 1024 + kc;
  p.h1 = hbf + (size_t)(m0 + 64 + r0) * 1024 + kc;
  p.b0 = Wc + (size_t)(n0 + r0) * KTOT + kc;
  p.b1 = Wc + (size_t)(n0 + 64 + r0) * KTOT + kc;

  GEMM_CORE(KSWITCH_STD)

  const bool zhalf = (n0 < 1024);
#pragma unroll
  for (int j = 0; j < 4; ++j) {
    const int gcn = n0 + wn * 64 + j * 16 + lrow;  // 0..2047
    const float bv = bias[gcn];
#pragma unroll
    for (int i = 0; i < 4; ++i) {
#pragma unroll
      for (int rg = 0; rg < 4; ++rg) {
        const int gr = m0 + wm * 64 + i * 16 + (lane >> 4) * 4 + rg;
        const float sv = sigmoid_f(acc[i][j][rg] + bv);
        if (zhalf) {
          zbuf[(size_t)gr * NU + gcn] = sv;
        } else {
          const int u = gcn - 1024;
          const float hv = bf2f(hbf[(size_t)gr * NU + u]);
          rh[(size_t)gr * NU + u] = f2bf(sv * hv);
        }
      }
    }
  }
}

// ---- phase 2: candidate GEMM (N=1024) + gating ----
__global__ __launch_bounds__(256, 3) void cand_kernel(
    const short* __restrict__ xbf, const short* __restrict__ rh,
    const short* __restrict__ Wc, const float* __restrict__ bias,
    const int* __restrict__ reset, const float* __restrict__ state,
    const float* __restrict__ zbuf, float* __restrict__ out) {
  __shared__ short sA[128][32];
  __shared__ short sB[128][32];
  const int tid = threadIdx.x;
  const int widx = (blockIdx.x & 7) * 64 + (blockIdx.x >> 3);
  const int m0 = (widx >> 3) * 128;       // 64 M-tiles
  const int n0 = (widx & 7) * 128;        // 8 N-tiles over 1024

  const int r0 = tid >> 2;
  const int kc = (tid & 3) * 8;
  const short* Wa = Wc + (size_t)2048 * KTOT;  // candidate weight rows
  TilePtrs p;
  p.a0 = xbf + (size_t)(m0 + r0) * 1024 + kc;
  p.a1 = xbf + (size_t)(m0 + 64 + r0) * 1024 + kc;
  p.h0 = rh + (size_t)(m0 + r0) * 1024 + kc;
  p.h1 = rh + (size_t)(m0 + 64 + r0) * 1024 + kc;
  p.b0 = Wa + (size_t)(n0 + r0) * KTOT + kc;
  p.b1 = Wa + (size_t)(n0 + 64 + r0) * KTOT + kc;

  GEMM_CORE(KSWITCH_STD)

#pragma unroll
  for (int j = 0; j < 4; ++j) {
    const int gc = n0 + wn * 64 + j * 16 + lrow;  // 0..1023
    const float ba = bias[2048 + gc];
#pragma unroll
    for (int i = 0; i < 4; ++i) {
#pragma unroll
      for (int rg = 0; rg < 4; ++rg) {
        const int gr = m0 + wm * 64 + i * 16 + (lane >> 4) * 4 + rg;
        const float av = tanh_f(acc[i][j][rg] + ba);
        const float zv = zbuf[(size_t)gr * NU + gc];
        const float hv = reset[gr] ? 0.f : state[(size_t)gr * NU + gc];
        const float hn = (1.f - zv) * hv + zv * av;
        out[(size_t)gr * NU + gc] = hn;
        out[(size_t)MROWS * NU + (size_t)gr * NU + gc] = hn;  // same addr as zbuf read (read-first, same thread)
      }
    }
  }
}

extern "C" void kernel_launch(void* const* d_in, const int* in_sizes, int n_in,
                              void* d_out, int out_size, void* d_ws, size_t ws_size,
                              hipStream_t stream) {
  const float* x = (const float*)d_in[0];      // 8192x1024
  const int* reset = (const int*)d_in[1];      // 8192
  const float* state = (const float*)d_in[2];  // 8192x1024
  const float* w_i = (const float*)d_in[3];    // 1024x3072
  const float* w_h = (const float*)d_in[4];    // 1024x3072
  const float* bias = (const float*)d_in[5];   // 3072
  float* out = (float*)d_out;                  // 2 x 8192x1024 fp32

  short* Wc = (short*)d_ws;                         // [3072][2048] bf16, 12MB
  short* xbf = Wc + (size_t)3072 * KTOT;            // 16MB
  short* hbf = xbf + (size_t)MROWS * 1024;          // 16MB
  short* rh  = hbf + (size_t)MROWS * 1024;          // 16MB
  float* zbuf = out + (size_t)MROWS * NU;           // z in d_out 2nd half

  wt_kernel<<<dim3(KTOT / 32, 3072 / 32), 256, 0, stream>>>(w_i, w_h, Wc);
  xh_kernel<<<dim3(MROWS * 1024 / 4 / 256), 256, 0, stream>>>(x, reset, state, xbf, hbf);

  zr_kernel<<<dim3(64 * 16), 256, 0, stream>>>(xbf, hbf, Wc, bias, zbuf, rh);
  cand_kernel<<<dim3(64 * 8), 256, 0, stream>>>(xbf, rh, Wc, bias, reset, state, zbuf, out);
}

// Round 4
// 184.342 us; speedup vs baseline: 1.7413x; 1.0669x over previous
//
#include <hip/hip_runtime.h>

// B=64,T=128,D=U=1024. M=8192 independent rows.
//   h' = reset?0:state
//   z = sig(x@wi_z + h'@wh_z + bz); r = sig(x@wi_r + h'@wh_r + br)
//   a = tanh(x@wi_a + (r*h')@wh_a + ba)   // (r*h') @ w  — * binds left of @
//   h_new = (1-z)h' + z*a; out = [h_new, h_new]
// Round 4: BM=128 x BN=256, BK=64, 8 waves, TRIPLE-buffered LDS (48KB x 3),
// counted vmcnt(6), one barrier per K-tile, XOR-swizzled LDS rows, setprio.
//   zr:   GEMM M8192 N2048 K2048 (A = xh_cat = [x|h'] rows), epi -> z fp32
//         (d_out 2nd half) + rh bf16
//   cand: GEMM M8192 N1024 K2048 (A = [x | rh]), epi -> gating, both outputs
// ws: Wc[3072][2048] 12MB + xh_cat[8192][2048] 32MB + rh[8192][1024] 16MB = 60MB

typedef __attribute__((ext_vector_type(8))) short short8;
typedef __attribute__((ext_vector_type(4))) short short4v;
typedef __attribute__((ext_vector_type(4))) float floatx4;
typedef __attribute__((ext_vector_type(4))) float f32x4;

#define MROWS 8192
#define KTOT 2048
#define NU 1024
#define NTILE 32          // K-tiles of 64
#define ABYTES 16384      // A region per buffer: 128 rows x 128B
#define BUFBYTES 49152    // A 16KB + B 32KB
#define LDSTOT (3 * BUFBYTES)

__device__ __forceinline__ short f2bf(float f) {
  unsigned u = __builtin_bit_cast(unsigned, f);
  u += 0x7fffu + ((u >> 16) & 1u);  // RNE
  return (short)(u >> 16);
}
__device__ __forceinline__ float bf2f(short s) {
  unsigned u = ((unsigned)(unsigned short)s) << 16;
  return __builtin_bit_cast(float, u);
}
__device__ __forceinline__ float sigmoid_f(float v) { return 1.f / (1.f + __expf(-v)); }
__device__ __forceinline__ float tanh_f(float v) {
  float c = fminf(fmaxf(v, -15.f), 15.f);
  float e = __expf(2.f * c);
  return (e - 1.f) / (e + 1.f);
}

typedef __attribute__((address_space(3))) void* lds_vp;
typedef const __attribute__((address_space(1))) void* gbl_vp;
__device__ __forceinline__ void gload16(const void* g, void* lds) {
  __builtin_amdgcn_global_load_lds((gbl_vp)g, (lds_vp)lds, 16, 0, 0);
}

#define MF(a, b, c) __builtin_amdgcn_mfma_f32_16x16x32_bf16(a, b, c, 0, 0, 0)
#define VMCNT(n) asm volatile("s_waitcnt vmcnt(" #n ")" ::: "memory")
#define TILE_BAR()                          \
  do {                                      \
    __builtin_amdgcn_s_barrier();           \
    asm volatile("" ::: "memory");          \
  } while (0)

// ---- prep 1: Wc[n][k] = (k<1024 ? w_i[k][n] : w_h[k-1024][n]) bf16 ----
__global__ __launch_bounds__(256) void wt_kernel(const float* __restrict__ w_i,
                                                 const float* __restrict__ w_h,
                                                 short* __restrict__ Wc) {
  __shared__ float tile[32][33];
  const int kb = blockIdx.x * 32;  // 0..2047
  const int nb = blockIdx.y * 32;  // 0..3071
  const float* src = (kb < 1024) ? w_i : w_h;
  const int kbl = kb & 1023;
  const int tx = threadIdx.x & 31;
  const int ty = threadIdx.x >> 5;
#pragma unroll
  for (int r = 0; r < 32; r += 8)
    tile[ty + r][tx] = src[(size_t)(kbl + ty + r) * 3072 + nb + tx];
  __syncthreads();
#pragma unroll
  for (int r = 0; r < 32; r += 8)
    Wc[(size_t)(nb + ty + r) * KTOT + kb + tx] = f2bf(tile[tx][ty + r]);
}

// ---- prep 2: xh_cat[m] = [bf16(x[m]) | bf16(reset?0:state[m])] ----
__global__ __launch_bounds__(256) void xh_kernel(const float* __restrict__ x,
                                                 const int* __restrict__ reset,
                                                 const float* __restrict__ state,
                                                 short* __restrict__ xhc) {
  const size_t i4 = (size_t)blockIdx.x * blockDim.x + threadIdx.x;
  const size_t e = i4 * 4;
  const int row = (int)(e >> 10);
  const int d = (int)(e & 1023);
  const float hm = reset[row] ? 0.f : 1.f;
  floatx4 fx = *(const floatx4*)(x + e);
  floatx4 fh = *(const floatx4*)(state + e);
  short4v cx, ch;
#pragma unroll
  for (int k = 0; k < 4; ++k) { cx[k] = f2bf(fx[k]); ch[k] = f2bf(fh[k] * hm); }
  *(short4v*)(xhc + (size_t)row * KTOT + d) = cx;
  *(short4v*)(xhc + (size_t)row * KTOT + 1024 + d) = ch;
}

// ---- GEMM core pieces (shared by zr / cand) ----
#define GEMM_PRELUDE()                                                        \
  extern __shared__ char lds[];                                               \
  const int tid = threadIdx.x;                                                \
  const int wave = tid >> 6, lane = tid & 63;                                 \
  const int wm = wave >> 2, wn = wave & 3;                                    \
  const int lrow = lane & 15;                                                 \
  const int g16 = (lane >> 4) << 4;                                           \
  const int swz = (lrow & 7) << 4;                                            \
  const int inner16 = (((lane & 7) ^ (lane >> 3)) << 4);                      \
  const int lr8 = lane >> 3;                                                  \
  const int dA0 = (2 * wave) * 1024, dA1 = dA0 + 1024;                        \
  const int dB00 = ABYTES + (4 * wave) * 1024, dB01 = dB00 + 1024,            \
            dB10 = dB00 + 2048, dB11 = dB00 + 3072;                           \
  f32x4 acc[4][4];                                                            \
  _Pragma("unroll") for (int i = 0; i < 4; ++i)                               \
      _Pragma("unroll") for (int j = 0; j < 4; ++j)                           \
          acc[i][j] = (f32x4){0.f, 0.f, 0.f, 0.f};

// read 4 A-frags + 4 B-frags for kstep K from bufC (swizzled)
#define LOAD_FRAGS(bufC, K)                                                   \
  {                                                                           \
    const int colb = (((K) * 64 + g16) ^ swz);                                \
    const char* pA = (bufC) + (wm * 64 + lrow) * 128 + colb;                  \
    const char* pB = (bufC) + ABYTES + (wn * 64 + lrow) * 128 + colb;         \
    af0 = *(const short8*)(pA);                                               \
    af1 = *(const short8*)(pA + 2048);                                        \
    af2 = *(const short8*)(pA + 4096);                                        \
    af3 = *(const short8*)(pA + 6144);                                        \
    bq0 = *(const short8*)(pB);                                               \
    bq1 = *(const short8*)(pB + 2048);                                        \
    bq2 = *(const short8*)(pB + 4096);                                        \
    bq3 = *(const short8*)(pB + 6144);                                        \
  }

#define MFMA16()                                 \
  __builtin_amdgcn_s_setprio(1);                 \
  acc[0][0] = MF(af0, bq0, acc[0][0]);           \
  acc[0][1] = MF(af0, bq1, acc[0][1]);           \
  acc[0][2] = MF(af0, bq2, acc[0][2]);           \
  acc[0][3] = MF(af0, bq3, acc[0][3]);           \
  acc[1][0] = MF(af1, bq0, acc[1][0]);           \
  acc[1][1] = MF(af1, bq1, acc[1][1]);           \
  acc[1][2] = MF(af1, bq2, acc[1][2]);           \
  acc[1][3] = MF(af1, bq3, acc[1][3]);           \
  acc[2][0] = MF(af2, bq0, acc[2][0]);           \
  acc[2][1] = MF(af2, bq1, acc[2][1]);           \
  acc[2][2] = MF(af2, bq2, acc[2][2]);           \
  acc[2][3] = MF(af2, bq3, acc[2][3]);           \
  acc[3][0] = MF(af3, bq0, acc[3][0]);           \
  acc[3][1] = MF(af3, bq1, acc[3][1]);           \
  acc[3][2] = MF(af3, bq2, acc[3][2]);           \
  acc[3][3] = MF(af3, bq3, acc[3][3]);           \
  __builtin_amdgcn_s_setprio(0);

// main pipelined loop; STG_H0/STG_H1 must be defined before use
#define GEMM_LOOP()                                                           \
  STG_H0(0, lds);                                                             \
  STG_H1(0, lds);                                                             \
  STG_H0(1, lds + BUFBYTES);                                                  \
  STG_H1(1, lds + BUFBYTES);                                                  \
  VMCNT(6);                                                                   \
  TILE_BAR();                                                                 \
  int cb = 0;                                                                 \
  for (int t = 0; t < NTILE; ++t) {                                           \
    char* bufC = lds + cb * BUFBYTES;                                         \
    int nbi = cb + 2;                                                         \
    if (nbi >= 3) nbi -= 3;                                                   \
    char* bufN = lds + nbi * BUFBYTES;                                        \
    const bool st = (t + 2 < NTILE);                                          \
    short8 af0, af1, af2, af3, bq0, bq1, bq2, bq3;                            \
    LOAD_FRAGS(bufC, 0);                                                      \
    if (st) { STG_H0(t + 2, bufN); }                                          \
    MFMA16();                                                                 \
    LOAD_FRAGS(bufC, 1);                                                      \
    if (st) { STG_H1(t + 2, bufN); }                                          \
    MFMA16();                                                                 \
    if (t < NTILE - 1) {                                                      \
      if (st) { VMCNT(6); } else { VMCNT(0); }                                \
      TILE_BAR();                                                             \
    }                                                                         \
    cb = (cb == 2) ? 0 : cb + 1;                                              \
  }

// ---- phase 1: zr GEMM (N=2048) ----
__global__ __launch_bounds__(512, 1) void zr_kernel(
    const short* __restrict__ xhc, const short* __restrict__ Wc,
    const float* __restrict__ bias, float* __restrict__ zbuf,
    short* __restrict__ rh) {
  GEMM_PRELUDE();
  const int ntile = blockIdx.x & 7;   // one N-column per XCD (B panel L2-resident)
  const int mtile = blockIdx.x >> 3;  // 0..63
  const int m0 = mtile * 128;
  const int n0g = ntile * 256;

  const short* aS0 = xhc + (size_t)(m0 + 16 * wave + lr8) * KTOT + (inner16 >> 1);
  const short* aS1 = aS0 + (size_t)8 * KTOT;
  const short* bS00 = Wc + (size_t)(n0g + 32 * wave + lr8) * KTOT + (inner16 >> 1);
  const short* bS01 = bS00 + (size_t)8 * KTOT;
  const short* bS10 = bS00 + (size_t)16 * KTOT;
  const short* bS11 = bS00 + (size_t)24 * KTOT;

#define STG_H0(T, BUF)                          \
  gload16(aS0 + (T) * 64, (BUF) + dA0);         \
  gload16(bS00 + (T) * 64, (BUF) + dB00);       \
  gload16(bS01 + (T) * 64, (BUF) + dB01);
#define STG_H1(T, BUF)                          \
  gload16(aS1 + (T) * 64, (BUF) + dA1);         \
  gload16(bS10 + (T) * 64, (BUF) + dB10);       \
  gload16(bS11 + (T) * 64, (BUF) + dB11);

  GEMM_LOOP();
#undef STG_H0
#undef STG_H1

  const bool zh = (n0g < 1024);
#pragma unroll
  for (int j = 0; j < 4; ++j) {
    const int gcn = n0g + wn * 64 + j * 16 + lrow;  // 0..2047
    const float bv = bias[gcn];
#pragma unroll
    for (int i = 0; i < 4; ++i) {
#pragma unroll
      for (int rg = 0; rg < 4; ++rg) {
        const int gr = m0 + wm * 64 + i * 16 + (lane >> 4) * 4 + rg;
        const float sv = sigmoid_f(acc[i][j][rg] + bv);
        if (zh) {
          zbuf[(size_t)gr * NU + gcn] = sv;
        } else {
          const int u = gcn - 1024;
          const float hv = bf2f(xhc[(size_t)gr * KTOT + 1024 + u]);
          rh[(size_t)gr * NU + u] = f2bf(sv * hv);
        }
      }
    }
  }
}

// ---- phase 2: candidate GEMM (N=1024) + gating ----
__global__ __launch_bounds__(512, 1) void cand_kernel(
    const short* __restrict__ xhc, const short* __restrict__ rh,
    const short* __restrict__ Wc, const float* __restrict__ bias,
    const int* __restrict__ reset, const float* __restrict__ state,
    const float* zbuf, float* out) {  // zbuf/out alias d_out: no restrict
  GEMM_PRELUDE();
  const int widx = (blockIdx.x & 7) * 32 + (blockIdx.x >> 3);
  const int ntile = widx >> 6;  // 0..3 (two XCDs share an N-column)
  const int mtile = widx & 63;
  const int m0 = mtile * 128;
  const int n0g = ntile * 256;

  const short* aX0 = xhc + (size_t)(m0 + 16 * wave + lr8) * KTOT + (inner16 >> 1);
  const short* aX1 = aX0 + (size_t)8 * KTOT;
  const short* aR0 = rh + (size_t)(m0 + 16 * wave + lr8) * NU + (inner16 >> 1);
  const short* aR1 = aR0 + (size_t)8 * NU;
  const short* Wa = Wc + (size_t)2048 * KTOT;
  const short* bS00 = Wa + (size_t)(n0g + 32 * wave + lr8) * KTOT + (inner16 >> 1);
  const short* bS01 = bS00 + (size_t)8 * KTOT;
  const short* bS10 = bS00 + (size_t)16 * KTOT;
  const short* bS11 = bS00 + (size_t)24 * KTOT;

#define STG_H0(T, BUF)                                                        \
  gload16((T) < 16 ? (aX0 + (T) * 64) : (aR0 + ((T) - 16) * 64), (BUF) + dA0);\
  gload16(bS00 + (T) * 64, (BUF) + dB00);                                     \
  gload16(bS01 + (T) * 64, (BUF) + dB01);
#define STG_H1(T, BUF)                                                        \
  gload16((T) < 16 ? (aX1 + (T) * 64) : (aR1 + ((T) - 16) * 64), (BUF) + dA1);\
  gload16(bS10 + (T) * 64, (BUF) + dB10);                                     \
  gload16(bS11 + (T) * 64, (BUF) + dB11);

  GEMM_LOOP();
#undef STG_H0
#undef STG_H1

#pragma unroll
  for (int j = 0; j < 4; ++j) {
    const int gc = n0g + wn * 64 + j * 16 + lrow;  // 0..1023
    const float ba = bias[2048 + gc];
#pragma unroll
    for (int i = 0; i < 4; ++i) {
#pragma unroll
      for (int rg = 0; rg < 4; ++rg) {
        const int gr = m0 + wm * 64 + i * 16 + (lane >> 4) * 4 + rg;
        const float av = tanh_f(acc[i][j][rg] + ba);
        const float zv = zbuf[(size_t)gr * NU + gc];
        const float hv = reset[gr] ? 0.f : state[(size_t)gr * NU + gc];
        const float hn = (1.f - zv) * hv + zv * av;
        out[(size_t)gr * NU + gc] = hn;
        out[(size_t)MROWS * NU + (size_t)gr * NU + gc] = hn;  // overwrites zbuf slot (read-first, same thread)
      }
    }
  }
}

extern "C" void kernel_launch(void* const* d_in, const int* in_sizes, int n_in,
                              void* d_out, int out_size, void* d_ws, size_t ws_size,
                              hipStream_t stream) {
  const float* x = (const float*)d_in[0];      // 8192x1024
  const int* reset = (const int*)d_in[1];      // 8192
  const float* state = (const float*)d_in[2];  // 8192x1024
  const float* w_i = (const float*)d_in[3];    // 1024x3072
  const float* w_h = (const float*)d_in[4];    // 1024x3072
  const float* bias = (const float*)d_in[5];   // 3072
  float* out = (float*)d_out;                  // 2 x 8192x1024 fp32

  short* Wc = (short*)d_ws;                    // [3072][2048] bf16, 12MB
  short* xhc = Wc + (size_t)3072 * KTOT;       // [8192][2048] bf16, 32MB
  short* rh = xhc + (size_t)MROWS * KTOT;      // [8192][1024] bf16, 16MB
  float* zbuf = out + (size_t)MROWS * NU;      // z in d_out 2nd half

  hipFuncSetAttribute(reinterpret_cast<const void*>(zr_kernel),
                      hipFuncAttributeMaxDynamicSharedMemorySize, LDSTOT);
  hipFuncSetAttribute(reinterpret_cast<const void*>(cand_kernel),
                      hipFuncAttributeMaxDynamicSharedMemorySize, LDSTOT);

  wt_kernel<<<dim3(KTOT / 32, 3072 / 32), 256, 0, stream>>>(w_i, w_h, Wc);
  xh_kernel<<<dim3(MROWS * 1024 / 4 / 256), 256, 0, stream>>>(x, reset, state, xhc);

  zr_kernel<<<dim3(512), 512, LDSTOT, stream>>>(xhc, Wc, bias, zbuf, rh);
  cand_kernel<<<dim3(256), 512, LDSTOT, stream>>>(xhc, rh, Wc, bias, reset, state, zbuf, out);
}